// Round 2
// baseline (116.693 us; speedup 1.0000x reference)
//
#include <hip/hip_runtime.h>
#include <math.h>

#define N0v 128
#define B1v 16
#define B2v 16
#define N1v 2048
#define N2v 32768
#define TOTALv 34944
#define BATCHv 1024
#define NEGV -100000000.0f

// ---- block-wide sum over 256 threads (4 waves of 64) ----
__device__ __forceinline__ float blockSum(float v, float* s_red, float* s_out) {
    __syncthreads();
    #pragma unroll
    for (int off = 32; off; off >>= 1) v += __shfl_down(v, off);
    const int wid = threadIdx.x >> 6, lane = threadIdx.x & 63;
    if (lane == 0) s_red[wid] = v;
    __syncthreads();
    if (threadIdx.x == 0) s_out[0] = s_red[0] + s_red[1] + s_red[2] + s_red[3];
    __syncthreads();
    return s_out[0];
}

// 4 blocks per row; block j handles out1 f4-slice [32+j*128, 32+(j+1)*128)
// and out2 f4-slice [544+j*2048, 544+(j+1)*2048). Block 0 also copies out0
// and computes S0/Sg1/Sg2. pred0/pred1_in recomputed redundantly per block
// (128+16 extra L2-hot loads) so each block is fully independent.
__global__ __launch_bounds__(256) void fused_kernel(
    const float* __restrict__ outs, const int* __restrict__ labels,
    float* __restrict__ out, float* __restrict__ s1p, float* __restrict__ s2p,
    float* __restrict__ miscf, int* __restrict__ misci)
{
    const int row = blockIdx.x >> 2;
    const int j   = blockIdx.x & 3;
    const int tid = threadIdx.x;
    const float* rowp = outs + (size_t)row * TOTALv;
    float*       orow = out  + (size_t)row * TOTALv;
    const float4* rv4 = reinterpret_cast<const float4*>(rowp);
    float4*       ov4 = reinterpret_cast<float4*>(orow);
    const float4  neg4 = make_float4(NEGV, NEGV, NEGV, NEGV);

    __shared__ float s_red[4];
    __shared__ float s_wmax[2]; __shared__ int s_wmi[2];
    __shared__ float s_f[4];   // 0:max0  1:S0  2:s1out  3:s2out
    __shared__ int   s_i[2];   // 0:pred0 1:pred1_in
    __shared__ float s_g[2];   // Sg1, Sg2

    const int lab0 = labels[row * 3 + 0];
    const int lab1 = labels[row * 3 + 1];

    // ---- pred0 / max0 (tid<128 active; 2 waves) ----
    float v0 = -INFINITY;
    if (tid < N0v) v0 = rowp[tid];
    float mv = v0; int mi = tid;
    #pragma unroll
    for (int off = 32; off; off >>= 1) {
        float ov = __shfl_down(mv, off);
        int   oi = __shfl_down(mi, off);
        if (ov > mv || (ov == mv && oi < mi)) { mv = ov; mi = oi; }
    }
    if (tid < N0v && (tid & 63) == 0) { s_wmax[tid >> 6] = mv; s_wmi[tid >> 6] = mi; }
    __syncthreads();
    if (tid == 0) {
        float m0 = s_wmax[0]; int i0 = s_wmi[0];
        if (s_wmax[1] > m0 || (s_wmax[1] == m0 && s_wmi[1] < i0)) { m0 = s_wmax[1]; i0 = s_wmi[1]; }
        s_f[0] = m0; s_i[0] = i0;
    }
    __syncthreads();
    const float max0  = s_f[0];
    const int   pred0 = s_i[0];

    // ---- 16-wide group reductions ----
    if (tid < 16) {                       // group argmax at pred0
        float gp = rowp[N0v + pred0 * B1v + tid]; int gi = tid;
        #pragma unroll
        for (int off = 8; off; off >>= 1) {
            float ogp = __shfl_xor(gp, off, 16);
            int   ogi = __shfl_xor(gi, off, 16);
            if (ogp > gp || (ogp == gp && ogi < gi)) { gp = ogp; gi = ogi; }
        }
        if (tid == 0) s_i[1] = gi;
    } else if (tid < 32) {                // Sg1: group sumexp at lab0
        float eg = __expf(rowp[N0v + lab0 * B1v + (tid - 16)]);
        #pragma unroll
        for (int off = 8; off; off >>= 1) eg += __shfl_xor(eg, off, 16);
        if (tid == 16) s_g[0] = eg;
    } else if (tid < 48) {                // Sg2: group sumexp at lab1
        float eg = __expf(rowp[N0v + N1v + lab1 * B2v + (tid - 32)]);
        #pragma unroll
        for (int off = 8; off; off >>= 1) eg += __shfl_xor(eg, off, 16);
        if (tid == 32) s_g[1] = eg;
    }
    __syncthreads();
    const int pred1 = pred0 * B1v + s_i[1];

    // ---- out1 slice load (tid<128: one f4 each) ----
    const int p1 = 32 + j * 128 + tid;
    float4 a;
    if (tid < 128) a = rv4[p1];

    // ---- out2 slice: batch-issue 8 independent f4 loads ----
    const float4* b2 = rv4 + 544 + j * 2048;
    float4*       o2 = ov4 + 544 + j * 2048;
    const float4 x0 = b2[tid];        const float4 x1 = b2[tid + 256];
    const float4 x2 = b2[tid + 512];  const float4 x3 = b2[tid + 768];
    const float4 x4 = b2[tid + 1024]; const float4 x5 = b2[tid + 1280];
    const float4 x6 = b2[tid + 1536]; const float4 x7 = b2[tid + 1792];

    // ---- out1 process ----
    float s1 = 0.f;
    if (tid < 128) {
        s1 = __expf(a.x) + __expf(a.y) + __expf(a.z) + __expf(a.w);
        ov4[p1] = (((p1 - 32) >> 2) == pred0) ? a : neg4;
        if (j == 0) orow[tid] = v0;   // out0 copy
    }

    // ---- out2 process ----
    const int lp = j * 2048 + tid;    // local f4 index within out2
    float sA = 0.f, sB = 0.f;
    sA += __expf(x0.x)+__expf(x0.y)+__expf(x0.z)+__expf(x0.w);
    o2[tid       ] = (((lp       ) >> 2) == pred1) ? x0 : neg4;
    sB += __expf(x1.x)+__expf(x1.y)+__expf(x1.z)+__expf(x1.w);
    o2[tid +  256] = (((lp +  256) >> 2) == pred1) ? x1 : neg4;
    sA += __expf(x2.x)+__expf(x2.y)+__expf(x2.z)+__expf(x2.w);
    o2[tid +  512] = (((lp +  512) >> 2) == pred1) ? x2 : neg4;
    sB += __expf(x3.x)+__expf(x3.y)+__expf(x3.z)+__expf(x3.w);
    o2[tid +  768] = (((lp +  768) >> 2) == pred1) ? x3 : neg4;
    sA += __expf(x4.x)+__expf(x4.y)+__expf(x4.z)+__expf(x4.w);
    o2[tid + 1024] = (((lp + 1024) >> 2) == pred1) ? x4 : neg4;
    sB += __expf(x5.x)+__expf(x5.y)+__expf(x5.z)+__expf(x5.w);
    o2[tid + 1280] = (((lp + 1280) >> 2) == pred1) ? x5 : neg4;
    sA += __expf(x6.x)+__expf(x6.y)+__expf(x6.z)+__expf(x6.w);
    o2[tid + 1536] = (((lp + 1536) >> 2) == pred1) ? x6 : neg4;
    sB += __expf(x7.x)+__expf(x7.y)+__expf(x7.z)+__expf(x7.w);
    o2[tid + 1792] = (((lp + 1792) >> 2) == pred1) ? x7 : neg4;

    // ---- reductions + writeout ----
    const float S0  = blockSum((tid < N0v) ? __expf(v0 - max0) : 0.f, s_red, &s_f[1]);
    const float s1t = blockSum(s1, s_red, &s_f[2]);
    const float s2t = blockSum(sA + sB, s_red, &s_f[3]);
    if (tid == 0) {
        s1p[row * 4 + j] = s1t;
        s2p[row * 4 + j] = s2t;
        if (j == 0) {
            miscf[row * 4 + 0] = S0;
            miscf[row * 4 + 1] = max0;
            miscf[row * 4 + 2] = s_g[0];
            miscf[row * 4 + 3] = s_g[1];
            misci[row * 2 + 0] = pred0;
            misci[row * 2 + 1] = s_i[1];
        }
    }
}

__global__ __launch_bounds__(1024) void finalize_kernel(
    const float* __restrict__ outs, const int* __restrict__ labels,
    const float* __restrict__ s1p, const float* __restrict__ s2p,
    const float* __restrict__ miscf, const int* __restrict__ misci,
    float* __restrict__ out_loss)
{
    const int row = threadIdx.x;   // 1024 threads == BATCH rows
    const float S0   = miscf[row * 4 + 0];
    const float max0 = miscf[row * 4 + 1];
    const float Sg1  = miscf[row * 4 + 2];
    const float Sg2  = miscf[row * 4 + 3];
    const int pred0    = misci[row * 2 + 0];
    const int pred1_in = misci[row * 2 + 1];
    const int lab0 = labels[row * 3 + 0];
    const int lab1 = labels[row * 3 + 1];
    const int lab2 = labels[row * 3 + 2];
    const int r1 = lab1 - lab0 * B1v;
    const float S1 = s1p[row*4+0] + s1p[row*4+1] + s1p[row*4+2] + s1p[row*4+3];
    const float S2 = s2p[row*4+0] + s2p[row*4+1] + s2p[row*4+2] + s2p[row*4+3];
    const float* rowp = outs + (size_t)row * TOTALv;
    const float t0 = rowp[lab0];
    const float t1 = rowp[N0v + lab1];
    const float t2 = rowp[N0v + N1v + lab2];
    const bool found0 = (pred0 != lab0);
    const bool found1 = found0 || (pred1_in != r1);
    float loss = (__logf(S0) + max0 - t0)
               + ((found0 ? __logf(S1) : __logf(Sg1)) - t1)
               + ((found1 ? __logf(S2) : __logf(Sg2)) - t2);
    #pragma unroll
    for (int off = 32; off; off >>= 1) loss += __shfl_down(loss, off);
    __shared__ float sh[16];
    if ((threadIdx.x & 63) == 0) sh[threadIdx.x >> 6] = loss;
    __syncthreads();
    if (threadIdx.x == 0) {
        float t = 0.f;
        #pragma unroll
        for (int w = 0; w < 16; ++w) t += sh[w];
        *out_loss = t;
    }
}

extern "C" void kernel_launch(void* const* d_in, const int* in_sizes, int n_in,
                              void* d_out, int out_size, void* d_ws, size_t ws_size,
                              hipStream_t stream) {
    const float* outs   = (const float*)d_in[0];
    const int*   labels = (const int*)d_in[1];
    float*       out    = (float*)d_out;

    float* wsf   = (float*)d_ws;
    float* s1p   = wsf;             // 4096 floats
    float* s2p   = wsf + 4096;      // 4096 floats
    float* miscf = wsf + 8192;      // 4096 floats
    int*   misci = (int*)(wsf + 12288); // 2048 ints

    fused_kernel<<<BATCHv * 4, 256, 0, stream>>>(outs, labels, out, s1p, s2p, miscf, misci);
    finalize_kernel<<<1, 1024, 0, stream>>>(outs, labels, s1p, s2p, miscf, misci,
                                            out + (size_t)BATCHv * TOTALv);
}

// Round 3
// 53.464 us; speedup vs baseline: 2.1827x; 2.1827x over previous
//
#include <hip/hip_runtime.h>
#include <math.h>

#define N0v 128
#define B1v 16
#define B2v 16
#define N1v 2048
#define N2v 32768
#define TOTALv 34944
#define BATCHv 1024
#define NEGV -100000000.0f

typedef __attribute__((ext_vector_type(4))) float f32x4;

// One block (1024 threads = 16 waves) per row. Single pass:
// load everything (batched, sched_barrier-pinned), compute pred0/pred1,
// fused exp-sums + masked NT writes, per-row loss to partials.
__global__ __launch_bounds__(1024) void row_kernel(
    const float* __restrict__ outs, const int* __restrict__ labels,
    float* __restrict__ out, float* __restrict__ partials)
{
    const int b   = blockIdx.x;
    const int tid = threadIdx.x;
    const int wid = tid >> 6, lane = tid & 63;
    const float* rowp = outs + (size_t)b * TOTALv;
    float*       orow = out  + (size_t)b * TOTALv;
    const f32x4* rv4 = reinterpret_cast<const f32x4*>(rowp);
    f32x4*       ov4 = reinterpret_cast<f32x4*>(orow);
    const f32x4  neg4 = {NEGV, NEGV, NEGV, NEGV};

    __shared__ float s_wmax[2]; __shared__ int s_wmi[2];
    __shared__ float s_r[16][3];
    __shared__ float s_f[1];   // max0
    __shared__ int   s_i[2];   // pred0, pred1_in
    __shared__ float s_g[2];   // Sg1, Sg2

    const int lab0 = labels[b * 3 + 0];
    const int lab1 = labels[b * 3 + 1];
    const int lab2 = labels[b * 3 + 2];

    // ---------- load cluster: issue everything, keep it in flight ----------
    float v0 = -INFINITY;
    if (tid < N0v) v0 = rowp[tid];
    f32x4 a = {0.f, 0.f, 0.f, 0.f};
    if (tid < 512) a = rv4[32 + tid];              // out1: f4 [32,544)
    const f32x4* b2 = rv4 + 544;                   // out2: 8192 f4
    f32x4*       o2 = ov4 + 544;
    const f32x4 x0 = b2[tid];
    const f32x4 x1 = b2[tid + 1024];
    const f32x4 x2 = b2[tid + 2048];
    const f32x4 x3 = b2[tid + 3072];
    const f32x4 x4 = b2[tid + 4096];
    const f32x4 x5 = b2[tid + 5120];
    const f32x4 x6 = b2[tid + 6144];
    const f32x4 x7 = b2[tid + 7168];
    __builtin_amdgcn_sched_barrier(0);

    // ---------- pred0 / max0 (tid<128 live in waves 0,1) ----------
    float mv = v0; int mi = tid;
    #pragma unroll
    for (int off = 32; off; off >>= 1) {
        float ov = __shfl_down(mv, off);
        int   oi = __shfl_down(mi, off);
        if (ov > mv || (ov == mv && oi < mi)) { mv = ov; mi = oi; }
    }
    if (tid < N0v && lane == 0) { s_wmax[wid] = mv; s_wmi[wid] = mi; }
    __syncthreads();
    if (tid == 0) {
        float m0 = s_wmax[0]; int i0 = s_wmi[0];
        if (s_wmax[1] > m0 || (s_wmax[1] == m0 && s_wmi[1] < i0)) { m0 = s_wmax[1]; i0 = s_wmi[1]; }
        s_f[0] = m0; s_i[0] = i0;
    }
    __syncthreads();
    const float max0  = s_f[0];
    const int   pred0 = s_i[0];

    // ---------- 16-wide group reductions (all in wave 0) ----------
    if (tid < 16) {                       // group argmax at pred0
        float gp = rowp[N0v + pred0 * B1v + tid]; int gi = tid;
        #pragma unroll
        for (int off = 8; off; off >>= 1) {
            float ogp = __shfl_xor(gp, off, 16);
            int   ogi = __shfl_xor(gi, off, 16);
            if (ogp > gp || (ogp == gp && ogi < gi)) { gp = ogp; gi = ogi; }
        }
        if (tid == 0) s_i[1] = gi;
    } else if (tid < 32) {                // Sg1: group sumexp at lab0
        float eg = __expf(rowp[N0v + lab0 * B1v + (tid - 16)]);
        #pragma unroll
        for (int off = 8; off; off >>= 1) eg += __shfl_xor(eg, off, 16);
        if (tid == 16) s_g[0] = eg;
    } else if (tid < 48) {                // Sg2: group sumexp at lab1
        float eg = __expf(rowp[N0v + N1v + lab1 * B2v + (tid - 32)]);
        #pragma unroll
        for (int off = 8; off; off >>= 1) eg += __shfl_xor(eg, off, 16);
        if (tid == 32) s_g[1] = eg;
    }
    __syncthreads();
    const int pred1_in = s_i[1];
    const int pred1    = pred0 * B1v + pred1_in;

    // ---------- out0 + out1: exp-sum + masked NT write ----------
    float s1 = 0.f;
    if (tid < 512) {
        s1 = __expf(a.x) + __expf(a.y) + __expf(a.z) + __expf(a.w);
        __builtin_nontemporal_store((tid >> 2) == pred0 ? a : neg4, &ov4[32 + tid]);
        if (tid < N0v) __builtin_nontemporal_store(v0, &orow[tid]);
    }

    // ---------- out2: exp-sum + masked NT write ----------
    float s2 = 0.f;
    s2 += __expf(x0.x)+__expf(x0.y)+__expf(x0.z)+__expf(x0.w);
    __builtin_nontemporal_store(((tid       ) >> 2) == pred1 ? x0 : neg4, &o2[tid]);
    s2 += __expf(x1.x)+__expf(x1.y)+__expf(x1.z)+__expf(x1.w);
    __builtin_nontemporal_store(((tid + 1024) >> 2) == pred1 ? x1 : neg4, &o2[tid + 1024]);
    s2 += __expf(x2.x)+__expf(x2.y)+__expf(x2.z)+__expf(x2.w);
    __builtin_nontemporal_store(((tid + 2048) >> 2) == pred1 ? x2 : neg4, &o2[tid + 2048]);
    s2 += __expf(x3.x)+__expf(x3.y)+__expf(x3.z)+__expf(x3.w);
    __builtin_nontemporal_store(((tid + 3072) >> 2) == pred1 ? x3 : neg4, &o2[tid + 3072]);
    s2 += __expf(x4.x)+__expf(x4.y)+__expf(x4.z)+__expf(x4.w);
    __builtin_nontemporal_store(((tid + 4096) >> 2) == pred1 ? x4 : neg4, &o2[tid + 4096]);
    s2 += __expf(x5.x)+__expf(x5.y)+__expf(x5.z)+__expf(x5.w);
    __builtin_nontemporal_store(((tid + 5120) >> 2) == pred1 ? x5 : neg4, &o2[tid + 5120]);
    s2 += __expf(x6.x)+__expf(x6.y)+__expf(x6.z)+__expf(x6.w);
    __builtin_nontemporal_store(((tid + 6144) >> 2) == pred1 ? x6 : neg4, &o2[tid + 6144]);
    s2 += __expf(x7.x)+__expf(x7.y)+__expf(x7.z)+__expf(x7.w);
    __builtin_nontemporal_store(((tid + 7168) >> 2) == pred1 ? x7 : neg4, &o2[tid + 7168]);

    // ---------- triple block reduction over 16 waves ----------
    float r0 = (tid < N0v) ? __expf(v0 - max0) : 0.f;
    #pragma unroll
    for (int off = 32; off; off >>= 1) {
        r0 += __shfl_down(r0, off);
        s1 += __shfl_down(s1, off);
        s2 += __shfl_down(s2, off);
    }
    if (lane == 0) { s_r[wid][0] = r0; s_r[wid][1] = s1; s_r[wid][2] = s2; }
    __syncthreads();
    if (tid == 0) {
        float S0 = 0.f, S1 = 0.f, S2 = 0.f;
        #pragma unroll
        for (int w = 0; w < 16; ++w) { S0 += s_r[w][0]; S1 += s_r[w][1]; S2 += s_r[w][2]; }
        const float Sg1 = s_g[0], Sg2 = s_g[1];
        const int r1 = lab1 - lab0 * B1v;
        const bool found0 = (pred0 != lab0);
        const bool found1 = found0 || (pred1_in != r1);
        const float t0 = rowp[lab0];
        const float t1 = rowp[N0v + lab1];
        const float t2 = rowp[N0v + N1v + lab2];
        const float loss0 = __logf(S0) + max0 - t0;
        const float loss1 = (found0 ? __logf(S1) : __logf(Sg1)) - t1;
        const float loss2 = (found1 ? __logf(S2) : __logf(Sg2)) - t2;
        partials[b] = loss0 + loss1 + loss2;
    }
}

__global__ __launch_bounds__(256) void loss_reduce(
    const float* __restrict__ partials, float* __restrict__ out_loss)
{
    __shared__ float sh[4];
    const int tid = threadIdx.x;
    float s = 0.f;
    for (int i = tid; i < BATCHv; i += 256) s += partials[i];
    #pragma unroll
    for (int off = 32; off; off >>= 1) s += __shfl_down(s, off);
    if ((tid & 63) == 0) sh[tid >> 6] = s;
    __syncthreads();
    if (tid == 0) *out_loss = sh[0] + sh[1] + sh[2] + sh[3];
}

extern "C" void kernel_launch(void* const* d_in, const int* in_sizes, int n_in,
                              void* d_out, int out_size, void* d_ws, size_t ws_size,
                              hipStream_t stream) {
    const float* outs   = (const float*)d_in[0];
    const int*   labels = (const int*)d_in[1];
    float*       out    = (float*)d_out;
    float*       part   = (float*)d_ws;

    row_kernel<<<BATCHv, 1024, 0, stream>>>(outs, labels, out, part);
    loss_reduce<<<1, 256, 0, stream>>>(part, out + (size_t)BATCHv * TOTALv);
}